// Round 7
// baseline (117.571 us; speedup 1.0000x reference)
//
#include <hip/hip_runtime.h>
#include <hip/hip_fp16.h>

// Problem constants (fixed by the reference setup)
#define NB 8
#define KF 16
#define HGT 256
#define WID 256
#define HW (HGT * WID)          // 65536
#define NPIX (NB * HW)          // 524288
#define NPTS 100000
#define NCH 4

// ---------------------------------------------------------------------------
// Kernel 1: transpose + pack ptclds (C,P) f32 -> (P) 4xfp16 (8B per point).
// fp16 error <= 2^-12/feature, weights sum <= 1 -> absmax impact ~3e-4
// (threshold 2e-2). 800KB table is L2-resident per XCD.
// ---------------------------------------------------------------------------
__global__ void ptclds_pack_kernel(const float* __restrict__ pt,
                                   uint2* __restrict__ ws) {
    int p = blockIdx.x * blockDim.x + threadIdx.x;
    if (p < NPTS) {
        __half2 h01 = __floats2half2_rn(pt[p],            pt[NPTS + p]);
        __half2 h23 = __floats2half2_rn(pt[2 * NPTS + p], pt[3 * NPTS + p]);
        uint2 q;
        q.x = *reinterpret_cast<unsigned int*>(&h01);
        q.y = *reinterpret_cast<unsigned int*>(&h23);
        ws[p] = q;
    }
}

// ---------------------------------------------------------------------------
// Kernel 2: compositing, 1 pixel per thread, PREDICATED gathers:
// invalid lanes (f<0, ~50% on average) are exec-masked OFF the gather so the
// TA/coalescer never sees their addresses (R7 discriminating experiment).
// Streams (frags/alphas) stay unconditional+coalesced.
// NO nontemporal builtins (R3 lesson: nt stores race the 0xAA poison fill).
// ---------------------------------------------------------------------------
template <bool PACKED>
__global__ __launch_bounds__(256, 6) void composite_kernel(
    const int* __restrict__ frags,     // (N,K,H,W)
    const float* __restrict__ alphas,  // (N,K,H,W)
    const float* __restrict__ pt,      // (C,P)  (used when !PACKED)
    const uint2* __restrict__ ws,      // (P) 4xfp16 (used when PACKED)
    const float* __restrict__ bg,      // (3,)
    float* __restrict__ out)           // (N,C,H,W)
{
    int i = blockIdx.x * blockDim.x + threadIdx.x;
    if (i >= NPIX) return;

    int n  = i >> 16;          // i / HW
    int hw = i & (HW - 1);     // i % HW

    long base = (long)n * KF * HW + hw;

    // Stage all fragment indices and alphas: 32 independent coalesced loads.
    int f[KF];
    float a[KF];
    #pragma unroll
    for (int k = 0; k < KF; ++k)
        f[k] = frags[base + (long)k * HW];
    #pragma unroll
    for (int k = 0; k < KF; ++k)
        a[k] = alphas[base + (long)k * HW];

    float4 acc = make_float4(0.f, 0.f, 0.f, 0.f);
    float T = 1.0f;

    #pragma unroll
    for (int k = 0; k < KF; ++k) {
        if (f[k] >= 0) {                // exec-masked: invalid lanes issue no gather
            float4 g;
            if (PACKED) {
                const uint2 q = ws[f[k]];
                const __half2 h01 = *reinterpret_cast<const __half2*>(&q.x);
                const __half2 h23 = *reinterpret_cast<const __half2*>(&q.y);
                const float2 g01 = __half22float2(h01);
                const float2 g23 = __half22float2(h23);
                g = make_float4(g01.x, g01.y, g23.x, g23.y);
            } else {
                g = make_float4(pt[f[k]], pt[NPTS + f[k]],
                                pt[2 * NPTS + f[k]], pt[3 * NPTS + f[k]]);
            }
            const float w = a[k] * T;
            acc.x += w * g.x;
            acc.y += w * g.y;
            acc.z += w * g.z;
            acc.w += w * g.w;
            T *= (1.0f - a[k]);
        }
    }

    // Background fill where no nearest point exists.
    if (f[0] < 0) acc = make_float4(bg[0], bg[1], bg[2], 1.0f);

    long ob = (long)n * NCH * HW + hw;
    out[ob]          = acc.x;
    out[ob + HW]     = acc.y;
    out[ob + 2 * HW] = acc.z;
    out[ob + 3 * HW] = acc.w;
}

extern "C" void kernel_launch(void* const* d_in, const int* in_sizes, int n_in,
                              void* d_out, int out_size, void* d_ws, size_t ws_size,
                              hipStream_t stream) {
    const int*   frags  = (const int*)d_in[0];    // fragments (N,K,H,W) int32
    const float* alphas = (const float*)d_in[1];  // alphas    (N,K,H,W) f32
    const float* pt     = (const float*)d_in[2];  // ptclds    (C,P)     f32
    const float* bg     = (const float*)d_in[3];  // background_color (3,) f32
    float* out = (float*)d_out;                   // (N,C,H,W) f32

    const bool packed = (ws_size >= (size_t)NPTS * sizeof(uint2));

    if (packed) {
        uint2* ws = (uint2*)d_ws;
        ptclds_pack_kernel<<<(NPTS + 255) / 256, 256, 0, stream>>>(pt, ws);
        composite_kernel<true><<<NPIX / 256, 256, 0, stream>>>(
            frags, alphas, pt, ws, bg, out);
    } else {
        composite_kernel<false><<<NPIX / 256, 256, 0, stream>>>(
            frags, alphas, pt, (const uint2*)nullptr, bg, out);
    }
}